// Round 12
// baseline (830.386 us; speedup 1.0000x reference)
//
#include <hip/hip_runtime.h>
#include <hip/hip_fp16.h>
#include <hip/hip_cooperative_groups.h>
#include <cstdint>
#include <cstddef>

namespace cg = cooperative_groups;

#define NNODES 8192
#define NEDGES 262144

typedef _Float16 f16x8 __attribute__((ext_vector_type(8)));
typedef _Float16 h2v   __attribute__((ext_vector_type(2)));
typedef float    f32x4 __attribute__((ext_vector_type(4)));

__device__ __forceinline__ float leaky(float v){ return v > 0.f ? v : 0.01f*v; }

__device__ __forceinline__ unsigned fmap(float f){
  unsigned u = __float_as_uint(f);
  return (u & 0x80000000u) ? ~u : (u | 0x80000000u);
}
__device__ __forceinline__ float funmap(unsigned u){
  return (u & 0x80000000u) ? __uint_as_float(u & 0x7FFFFFFFu) : __uint_as_float(~u);
}
__device__ __forceinline__ h2v as_h2(unsigned u){
  union{ unsigned x; h2v h; } c; c.x = u; return c.h;
}

// ================= k_pre: conversions / transposes / degrees / small vectors =======
__global__ __launch_bounds__(256) void k_pre(
    const float* __restrict__ x, const float* __restrict__ Wq, const float* __restrict__ Wk,
    const float* __restrict__ Wr, const float* __restrict__ W1, const float* __restrict__ W2,
    const float* __restrict__ W3, const float* __restrict__ bq, const float* __restrict__ bk,
    const int* __restrict__ ei, int E,
    __half* xh, __half* Wqh, __half* Wkh, __half* Wrt, __half* W1t, __half* W2t, __half* W3t,
    float* bqk, float* wb, float* s0p, int* degc, int* degr){
  int b = blockIdx.x, t = threadIdx.x;
  if (b < 1024){
    int base = (b*256 + t)*4;
    float4 xv = *(const float4*)(x + base);
    uint2 o;
    *(__half2*)&o.x = __floats2half2_rn(xv.x, xv.y);
    *(__half2*)&o.y = __floats2half2_rn(xv.z, xv.w);
    *(uint2*)(xh + base) = o;
  } else if (b < 1088){
    int base = ((b-1024)*256 + t)*4;
    float4 v = *(const float4*)(Wq + base);
    uint2 o;
    *(__half2*)&o.x = __floats2half2_rn(v.x, v.y);
    *(__half2*)&o.y = __floats2half2_rn(v.z, v.w);
    *(uint2*)(Wqh + base) = o;
  } else if (b < 1152){
    int base = ((b-1088)*256 + t)*4;
    float4 v = *(const float4*)(Wk + base);
    uint2 o;
    *(__half2*)&o.x = __floats2half2_rn(v.x, v.y);
    *(__half2*)&o.y = __floats2half2_rn(v.z, v.w);
    *(uint2*)(Wkh + base) = o;
  } else if (b < 1184){         // Wr[128][64] -> Wrt[64][128]
    int idx = (b-1152)*256 + t;
    int nn = idx >> 7, k = idx & 127;
    Wrt[idx] = __float2half(Wr[k*64 + nn]);
  } else if (b < 1248){         // W1[128][128] -> W1t[128][128]
    int idx = (b-1184)*256 + t;
    int nn = idx >> 7, k = idx & 127;
    W1t[idx] = __float2half(W1[k*128 + nn]);
  } else if (b < 1376){         // W2[128][256] -> W2t[256][128]
    int idx = (b-1248)*256 + t;
    int nn = idx >> 7, k = idx & 127;
    W2t[idx] = __float2half(W2[k*256 + nn]);
  } else if (b < 1440){         // W3[256][64] -> W3t[64][256]
    int idx = (b-1376)*256 + t;
    int nn = idx >> 8, k = idx & 255;
    W3t[idx] = __float2half(W3[k*64 + nn]);
  } else if (b < 2464){         // degrees
    int e = (b-1440)*256 + t;
    atomicAdd(&degc[ei[E+e]], 1);
    atomicAdd(&degr[ei[e]],   1);
  } else {                      // smallvec: coalesced row read + block reduce
    int c = b - 2464;
    __shared__ float ra[256], rb[256], rc[256];
    ra[t] = Wk[c*256 + t] * bq[t];
    rb[t] = Wq[c*256 + t] * bk[t];
    if (c == 0) rc[t] = bq[t]*bk[t];
    __syncthreads();
    for (int off=128; off; off>>=1){
      if (t < off){
        ra[t] += ra[t+off];
        rb[t] += rb[t+off];
        if (c == 0) rc[t] += rc[t+off];
      }
      __syncthreads();
    }
    if (t == 0){
      bqk[c] = ra[0];
      wb[c]  = rb[0];
      if (c == 0) s0p[0] = rc[0];
    }
  }
}

// ---------------- MFMA GEMM tile (device): C64x64 = A[.,K] @ Bt[.,K]^T ----------------
__device__ __forceinline__ void gemm_tile(const __half* __restrict__ A,
    const __half* __restrict__ Bt, const float* __restrict__ bias,
    float* __restrict__ Cf, __half* __restrict__ Ch, float* __restrict__ csum,
    int K, int N, int act, int bx, int by,
    _Float16 (*As)[40], _Float16 (*Bs)[40], float* cs){
  int t = threadIdx.x, w = t>>6, lane = t&63;
  int m0 = bx*64, n0 = by*64;
  int quad = lane>>4, l15 = lane&15;
  int srow = t>>2, soff = (t&3)*8;
  f32x4 acc0 = {0.f,0.f,0.f,0.f}, acc1 = acc0, acc2 = acc0, acc3 = acc0;
  for (int k0 = 0; k0 < K; k0 += 32){
    *(uint4*)&As[srow][soff] = *(const uint4*)(A  + (size_t)(m0+srow)*K + k0 + soff);
    *(uint4*)&Bs[srow][soff] = *(const uint4*)(Bt + (size_t)(n0+srow)*K + k0 + soff);
    __syncthreads();
    f16x8 af = *(const f16x8*)&As[w*16 + l15][quad*8];
    f16x8 b0 = *(const f16x8*)&Bs[ 0 + l15][quad*8];
    f16x8 b1 = *(const f16x8*)&Bs[16 + l15][quad*8];
    f16x8 b2 = *(const f16x8*)&Bs[32 + l15][quad*8];
    f16x8 b3 = *(const f16x8*)&Bs[48 + l15][quad*8];
    acc0 = __builtin_amdgcn_mfma_f32_16x16x32_f16(af, b0, acc0, 0,0,0);
    acc1 = __builtin_amdgcn_mfma_f32_16x16x32_f16(af, b1, acc1, 0,0,0);
    acc2 = __builtin_amdgcn_mfma_f32_16x16x32_f16(af, b2, acc2, 0,0,0);
    acc3 = __builtin_amdgcn_mfma_f32_16x16x32_f16(af, b3, acc3, 0,0,0);
    __syncthreads();
  }
  f32x4 accs[4] = {acc0, acc1, acc2, acc3};
  if (csum){
    if (t < 64) cs[t] = 0.f;
    __syncthreads();
    #pragma unroll
    for (int nt=0; nt<4; ++nt){
      float p = accs[nt][0]+accs[nt][1]+accs[nt][2]+accs[nt][3];
      atomicAdd(&cs[nt*16 + l15], p);
    }
    __syncthreads();
    if (t < 64) atomicAdd(&csum[n0 + t], cs[t]);
  }
  #pragma unroll
  for (int nt=0; nt<4; ++nt){
    int col = n0 + nt*16 + l15;
    float bv = bias ? bias[col] : 0.f;
    #pragma unroll
    for (int r=0;r<4;r++){
      int row = m0 + w*16 + quad*4 + r;
      float v = accs[nt][r] + bv;
      if (act) v = leaky(v);
      if (Cf) Cf[(size_t)row*N + col] = v;
      if (Ch) Ch[(size_t)row*N + col] = __float2half(v);
    }
  }
}

// ================= discrete fallback kernels (round-10 proven path) =================
__global__ __launch_bounds__(256) void k_scan(const int* __restrict__ degc,
    const int* __restrict__ degr, int* __restrict__ ptrc, int* __restrict__ ptrr,
    int* __restrict__ curc, int* __restrict__ curr, float* __restrict__ dinv, int n,
    const __half* __restrict__ xh, const __half* __restrict__ W1t, __half* xw1h){
  __shared__ _Float16 As[64][40];
  __shared__ _Float16 Bs[64][40];
  int b = blockIdx.x;
  if (b >= 2){
    int bb = b - 2;
    gemm_tile(xh, W1t, nullptr, nullptr, xw1h, nullptr, 128, 128, 0, bb>>1, bb&1, As, Bs, nullptr);
    return;
  }
  const int* deg = b ? degr : degc;
  int* ptr = b ? ptrr : ptrc;
  int* cur = b ? curr : curc;
  int t = threadIdx.x, lane = t & 63, wid = t >> 6;
  int base = t*32;
  int s = 0;
  for (int q=0;q<32;q++) s += deg[base+q];
  int sc = s;
  #pragma unroll
  for (int o=1;o<64;o<<=1){ int v = __shfl_up(sc, o, 64); if (lane >= o) sc += v; }
  __shared__ int wsum[4];
  __shared__ int woff[4];
  if (lane==63) wsum[wid] = sc;
  __syncthreads();
  if (t==0){ int r=0; for (int i=0;i<4;i++){ woff[i]=r; r+=wsum[i]; } }
  __syncthreads();
  int run = sc - s + woff[wid];
  for (int q=0;q<32;q++){
    ptr[base+q] = run;
    cur[base+q] = run;
    int d = deg[base+q];
    if (b==0) dinv[base+q] = rsqrtf((float)(d+1));
    run += d;
  }
  if (t==255) ptr[n] = run;
}

__global__ __launch_bounds__(256) void k_gemm(const __half* __restrict__ A,
    const __half* __restrict__ Bt, const float* __restrict__ bias,
    float* __restrict__ Cf, __half* __restrict__ Ch, float* __restrict__ csum,
    int K, int N, int act){
  __shared__ _Float16 As[64][40];
  __shared__ _Float16 Bs[64][40];
  __shared__ float cs[64];
  gemm_tile(A, Bt, bias, Cf, Ch, csum, K, N, act, blockIdx.x, blockIdx.y, As, Bs, cs);
}

__global__ __launch_bounds__(256) void k_mix1(const int* __restrict__ ei,
    int* curc, int* curr, int* csrc, int* csrd, int E,
    const __half* Wkh, const __half* Wqh, __half* Wqkt,
    const __half* xh, const __half* Wrt, const float* br, float* resid){
  __shared__ _Float16 As[64][40];
  __shared__ _Float16 Bs[64][40];
  int b = blockIdx.x;
  int SB = E/256;
  if (b < SB){
    int e = b*256 + threadIdx.x;
    int r = ei[e], c = ei[E+e];
    int p1 = atomicAdd(&curc[c],1); csrc[p1] = r;
    int p2 = atomicAdd(&curr[r],1); csrd[p2] = c;
  } else if (b < SB+16){
    int bb = b - SB;
    gemm_tile(Wkh, Wqh, nullptr, nullptr, Wqkt, nullptr, 256, 256, 0, bb&3, bb>>2, As, Bs, nullptr);
  } else {
    gemm_tile(xh, Wrt, br, resid, nullptr, nullptr, 128, 64, 0, b-(SB+16), 0, As, Bs, nullptr);
  }
}

__global__ __launch_bounds__(256) void k_mix2(const __half* h2h, const __half* W3t,
    __half* gh, float* sw3, const __half* Wqkt, const float* bqk, __half* qth){
  __shared__ _Float16 As[64][40];
  __shared__ _Float16 Bs[64][40];
  __shared__ float cs[64];
  int b = blockIdx.x;
  if (b < 128){
    gemm_tile(h2h, W3t, nullptr, nullptr, gh, sw3, 256, 64, 0, b, 0, As, Bs, cs);
  } else {
    int bb = b - 128;
    gemm_tile(h2h, Wqkt, bqk, nullptr, qth, nullptr, 256, 256, 0, bb>>2, bb&3, As, Bs, cs);
  }
}

__global__ __launch_bounds__(256) void k_agg4(const __half* __restrict__ in,
    const int* __restrict__ ptr, const int* __restrict__ src,
    const float* __restrict__ dinv, __half* __restrict__ outp,
    const float* __restrict__ bias, int act){
  int w = threadIdx.x>>6, lane = threadIdx.x&63;
  int c = blockIdx.x*4 + w;
  float dc = dinv[c];
  float2 acc = make_float2(0.f, 0.f);
  int e0 = ptr[c], e1 = ptr[c+1];
  for (int eb = e0; eb < e1; eb += 4){
    int m = e1 - eb; if (m > 4) m = 4;
    int r[4];
    #pragma unroll
    for (int u=0;u<4;u++) r[u] = src[(u<m) ? eb+u : eb];
    float sc[4]; __half2 hv[4];
    #pragma unroll
    for (int u=0;u<4;u++){
      sc[u] = dinv[r[u]];
      hv[u] = *(const __half2*)(in + (size_t)r[u]*128 + lane*2);
    }
    #pragma unroll
    for (int u=0;u<4;u++){
      if (u < m){
        float2 h = __half22float2(hv[u]);
        acc.x = fmaf(sc[u], h.x, acc.x);
        acc.y = fmaf(sc[u], h.y, acc.y);
      }
    }
  }
  float2 self = __half22float2(*(const __half2*)(in + (size_t)c*128 + lane*2));
  float ox = dc*(dc*self.x + acc.x);
  float oy = dc*(dc*self.y + acc.y);
  if (act){
    ox = leaky(ox + bias[lane*2]);
    oy = leaky(oy + bias[lane*2+1]);
  }
  *(__half2*)(outp + (size_t)c*128 + lane*2) = __floats2half2_rn(ox, oy);
}

__global__ __launch_bounds__(256) void k_attn6(const __half* __restrict__ h2h,
    const __half* __restrict__ qth, const __half* __restrict__ gh,
    const float* __restrict__ sw3, const float* __restrict__ wb,
    const float* __restrict__ s0p, const int* __restrict__ ptrr,
    const int* __restrict__ csrd, __half* __restrict__ hw3h, int n){
  int w = threadIdx.x>>6, lane = threadIdx.x&63;
  int i = blockIdx.x*4 + w;
  int fo = lane*4;
  uint2 qtu = *(const uint2*)(qth + (size_t)i*256 + fo);
  h2v q0 = as_h2(qtu.x), q1 = as_h2(qtu.y);
  float4 wbv = *(const float4*)(wb + fo);
  uint2 hiu  = *(const uint2*)(h2h + (size_t)i*256 + fo);
  float2 hia = __half22float2(*(__half2*)&hiu.x);
  float2 hib = __half22float2(*(__half2*)&hiu.y);
  float pv = hia.x*wbv.x + hia.y*wbv.y + hib.x*wbv.z + hib.y*wbv.w;
  #pragma unroll
  for (int mm=32; mm; mm>>=1) pv += __shfl_xor(pv, mm, 64);
  float Ei = __expf(pv + s0p[0]);
  int e0 = ptrr[i], e1 = ptrr[i+1];
  float acc = 0.f, dsum = 0.f;
  for (int eb = e0; eb < e1; eb += 8){
    int m = e1 - eb; if (m > 8) m = 8;
    int j[8];
    #pragma unroll
    for (int u=0;u<8;u++) j[u] = csrd[(u<m) ? eb+u : eb];
    uint2 hv[8]; float gv[8];
    #pragma unroll
    for (int u=0;u<8;u++){
      hv[u] = *(const uint2*)(h2h + (size_t)j[u]*256 + fo);
      gv[u] = __half2float(gh[(size_t)j[u]*64 + lane]);
    }
    float d[8];
    #pragma unroll
    for (int u=0;u<8;u++)
      d[u] = __builtin_amdgcn_fdot2(q1, as_h2(hv[u].y),
              __builtin_amdgcn_fdot2(q0, as_h2(hv[u].x), 0.f, false), false);
    #pragma unroll
    for (int mm=32; mm; mm>>=1){
      #pragma unroll
      for (int u=0;u<8;u++) d[u] += __shfl_xor(d[u], mm, 64);
    }
    #pragma unroll
    for (int u=0;u<8;u++){
      if (u < m){
        float we = Ei * __expf(d[u]);
        dsum += we;
        acc = fmaf(we - 1.f, gv[u], acc);
      }
    }
  }
  float inv = 1.0f / ((float)(n - (e1 - e0)) + dsum);
  hw3h[(size_t)i*64 + lane] = __float2half((sw3[lane] + acc) * inv);
}

__global__ __launch_bounds__(256) void k_zp4(const __half* __restrict__ hw3h,
    const float* __restrict__ b3, const int* __restrict__ ptrc,
    const int* __restrict__ csrc, const float* __restrict__ dinv,
    const float* __restrict__ resid, const float* __restrict__ lng,
    const float* __restrict__ lnb, unsigned* __restrict__ poolpart){
  int w = threadIdx.x>>6, lane = threadIdx.x&63;
  int c = blockIdx.x*4 + w;
  float dc = dinv[c];
  float acc = 0.f;
  int e0 = ptrc[c], e1 = ptrc[c+1];
  for (int eb = e0; eb < e1; eb += 4){
    int m = e1 - eb; if (m > 4) m = 4;
    int r[4];
    #pragma unroll
    for (int u=0;u<4;u++) r[u] = csrc[(u<m) ? eb+u : eb];
    float sc[4]; __half hval[4];
    #pragma unroll
    for (int u=0;u<4;u++){
      sc[u] = dinv[r[u]];
      hval[u] = hw3h[(size_t)r[u]*64 + lane];
    }
    #pragma unroll
    for (int u=0;u<4;u++)
      if (u < m) acc = fmaf(sc[u], __half2float(hval[u]), acc);
  }
  float self = __half2float(hw3h[(size_t)c*64 + lane]);
  float v = leaky(dc*(dc*self + acc) + b3[lane]) + resid[(size_t)c*64 + lane];
  float s = v;
  #pragma unroll
  for (int mm=32; mm; mm>>=1) s += __shfl_xor(s, mm, 64);
  float mu = s * (1.0f/64.0f);
  float d = v - mu;
  float s2 = d*d;
  #pragma unroll
  for (int mm=32; mm; mm>>=1) s2 += __shfl_xor(s2, mm, 64);
  float zv = d * rsqrtf(s2*(1.0f/64.0f) + 1e-5f) * lng[lane] + lnb[lane];
  atomicMax(&poolpart[(c & 63)*64 + lane], fmap(zv));
}

__global__ __launch_bounds__(256) void k_final(const unsigned* __restrict__ poolpart,
    const float* __restrict__ Wf, const float* __restrict__ bfv, float* __restrict__ out){
  int t = threadIdx.x, f = t & 63, g = t >> 6;
  unsigned mu = 0u;
  for (int b = g; b < 64; b += 4) mu = max(mu, poolpart[b*64 + f]);
  __shared__ unsigned sm[4][64];
  __shared__ float p[64];
  sm[g][f] = mu;
  __syncthreads();
  if (g == 0)
    p[f] = funmap(max(max(sm[0][f],sm[1][f]), max(sm[2][f],sm[3][f])));
  __syncthreads();
  if (t < 16){
    float a = bfv[t];
    #pragma unroll
    for (int ff=0; ff<64; ++ff) a = fmaf(p[ff], Wf[ff*16 + t], a);
    out[t] = a;
  }
}

// ---------------- mega-kernel params ----------------
struct MegaP {
  const int* ei; int E; int n;
  const __half* xh; const __half* W1t; __half* xw1h;
  const int* degc; const int* degr;
  int* ptrc; int* ptrr; int* curc; int* curr; float* dinv;
  int* csrc; int* csrd;
  const __half* Wkh; const __half* Wqh; __half* Wqkt;
  const __half* Wrt; const float* br; float* resid;
  const float* b1; __half* h1h; __half* h1ah;
  const __half* W2t; const float* b2; __half* h2h;
  const __half* W3t; __half* gh; float* sw3;
  const float* bqk; __half* qth;
  const float* wb; const float* s0p; __half* hw3h;
  const float* b3; const float* lng; const float* lnb;
  unsigned* poolpart;
  const float* Wf; const float* bfv; float* out;
};

// ============ cooperative mega-kernel: grid-stride phases, any grid size ============
__global__ __launch_bounds__(256, 2) void k_mega(MegaP p){
  cg::grid_group grid = cg::this_grid();
  __shared__ _Float16 As[64][40];
  __shared__ _Float16 Bs[64][40];
  __shared__ float cs[64];
  int b = blockIdx.x, t = threadIdx.x;
  int G = gridDim.x;
  int w = t>>6, lane = t&63;

  // ---- P1: scans (blocks 0,1) + xw1 = x@W1 (256 tiles, grid-stride) ----
  if (b < 2){
    const int* deg = b ? p.degr : p.degc;
    int* ptr = b ? p.ptrr : p.ptrc;
    int* cur = b ? p.curr : p.curc;
    int base = t*32;
    int s = 0;
    for (int q=0;q<32;q++) s += deg[base+q];
    int sc = s;
    #pragma unroll
    for (int o=1;o<64;o<<=1){ int v = __shfl_up(sc, o, 64); if (lane >= o) sc += v; }
    __shared__ int wsum[4];
    __shared__ int woff[4];
    if (lane==63) wsum[w] = sc;
    __syncthreads();
    if (t==0){ int r=0; for (int i=0;i<4;i++){ woff[i]=r; r+=wsum[i]; } }
    __syncthreads();
    int run = sc - s + woff[w];
    for (int q=0;q<32;q++){
      ptr[base+q] = run;
      cur[base+q] = run;
      int d = deg[base+q];
      if (b==0) p.dinv[base+q] = rsqrtf((float)(d+1));
      run += d;
    }
    if (t==255) ptr[p.n] = run;
    __syncthreads();
  }
  for (int u = b; u < 256; u += G)
    gemm_tile(p.xh, p.W1t, nullptr, nullptr, p.xw1h, nullptr, 128, 128, 0,
              u>>1, u&1, As, Bs, nullptr);
  grid.sync();

  // ---- P2: CSR scatter (1024) + Wqkt (16) + resid (128) ----
  for (int u = b; u < 1168; u += G){
    if (u < 1024){
      int e = u*256 + t;
      int r = p.ei[e], c = p.ei[p.E+e];
      int p1 = atomicAdd(&p.curc[c],1); p.csrc[p1] = r;
      int p2 = atomicAdd(&p.curr[r],1); p.csrd[p2] = c;
    } else if (u < 1040){
      int bb = u - 1024;
      gemm_tile(p.Wkh, p.Wqh, nullptr, nullptr, p.Wqkt, nullptr, 256, 256, 0,
                bb&3, bb>>2, As, Bs, nullptr);
    } else {
      gemm_tile(p.xh, p.Wrt, p.br, p.resid, nullptr, nullptr, 128, 64, 0,
                u-1040, 0, As, Bs, nullptr);
    }
  }
  grid.sync();

  // ---- P3: conv1 aggregate + bias + leaky -> h1 (wave-per-node) ----
  for (int g4 = b; g4 < 2048; g4 += G){
    int c = g4*4 + w;
    float dc = p.dinv[c];
    float2 acc = make_float2(0.f, 0.f);
    int e0 = p.ptrc[c], e1 = p.ptrc[c+1];
    for (int eb = e0; eb < e1; eb += 4){
      int m = e1 - eb; if (m > 4) m = 4;
      int r[4];
      #pragma unroll
      for (int u=0;u<4;u++) r[u] = p.csrc[(u<m) ? eb+u : eb];
      float sc[4]; __half2 hv[4];
      #pragma unroll
      for (int u=0;u<4;u++){
        sc[u] = p.dinv[r[u]];
        hv[u] = *(const __half2*)(p.xw1h + (size_t)r[u]*128 + lane*2);
      }
      #pragma unroll
      for (int u=0;u<4;u++){
        if (u < m){
          float2 h = __half22float2(hv[u]);
          acc.x = fmaf(sc[u], h.x, acc.x);
          acc.y = fmaf(sc[u], h.y, acc.y);
        }
      }
    }
    float2 self = __half22float2(*(const __half2*)(p.xw1h + (size_t)c*128 + lane*2));
    float ox = leaky(dc*(dc*self.x + acc.x) + p.b1[lane*2]);
    float oy = leaky(dc*(dc*self.y + acc.y) + p.b1[lane*2+1]);
    *(__half2*)(p.h1h + (size_t)c*128 + lane*2) = __floats2half2_rn(ox, oy);
  }
  grid.sync();

  // ---- P4: conv2 aggregate (pre-transform, 128-wide) ----
  for (int g4 = b; g4 < 2048; g4 += G){
    int c = g4*4 + w;
    float dc = p.dinv[c];
    float2 acc = make_float2(0.f, 0.f);
    int e0 = p.ptrc[c], e1 = p.ptrc[c+1];
    for (int eb = e0; eb < e1; eb += 4){
      int m = e1 - eb; if (m > 4) m = 4;
      int r[4];
      #pragma unroll
      for (int u=0;u<4;u++) r[u] = p.csrc[(u<m) ? eb+u : eb];
      float sc[4]; __half2 hv[4];
      #pragma unroll
      for (int u=0;u<4;u++){
        sc[u] = p.dinv[r[u]];
        hv[u] = *(const __half2*)(p.h1h + (size_t)r[u]*128 + lane*2);
      }
      #pragma unroll
      for (int u=0;u<4;u++){
        if (u < m){
          float2 h = __half22float2(hv[u]);
          acc.x = fmaf(sc[u], h.x, acc.x);
          acc.y = fmaf(sc[u], h.y, acc.y);
        }
      }
    }
    float2 self = __half22float2(*(const __half2*)(p.h1h + (size_t)c*128 + lane*2));
    *(__half2*)(p.h1ah + (size_t)c*128 + lane*2) =
        __floats2half2_rn(dc*(dc*self.x + acc.x), dc*(dc*self.y + acc.y));
  }
  grid.sync();

  // ---- P5: conv2 transform: h2 = leaky(h1a@W2 + b2), 512 tiles ----
  for (int u = b; u < 512; u += G)
    gemm_tile(p.h1ah, p.W2t, p.b2, nullptr, p.h2h, nullptr, 128, 256, 1,
              u>>2, u&3, As, Bs, nullptr);
  grid.sync();

  // ---- P6: G = h2@W3 (+colsum sw3) and qt = h2@Wqk + bqk, 640 tiles ----
  for (int u = b; u < 640; u += G){
    if (u < 128){
      gemm_tile(p.h2h, p.W3t, nullptr, nullptr, p.gh, p.sw3, 256, 64, 0, u, 0, As, Bs, cs);
    } else {
      int bb = u - 128;
      gemm_tile(p.h2h, p.Wqkt, p.bqk, nullptr, p.qth, nullptr, 256, 256, 0,
                bb>>2, bb&3, As, Bs, cs);
    }
  }
  grid.sync();

  // ---- P7: fused attention -> hw3h (wave-per-node, 8-edge ILP, fdot2) ----
  for (int g4 = b; g4 < 2048; g4 += G){
    int i = g4*4 + w;
    int fo = lane*4;
    uint2 qtu = *(const uint2*)(p.qth + (size_t)i*256 + fo);
    h2v q0 = as_h2(qtu.x), q1 = as_h2(qtu.y);
    float4 wbv = *(const float4*)(p.wb + fo);
    uint2 hiu  = *(const uint2*)(p.h2h + (size_t)i*256 + fo);
    float2 hia = __half22float2(*(__half2*)&hiu.x);
    float2 hib = __half22float2(*(__half2*)&hiu.y);
    float pv = hia.x*wbv.x + hia.y*wbv.y + hib.x*wbv.z + hib.y*wbv.w;
    #pragma unroll
    for (int mm=32; mm; mm>>=1) pv += __shfl_xor(pv, mm, 64);
    float Ei = __expf(pv + p.s0p[0]);
    int e0 = p.ptrr[i], e1 = p.ptrr[i+1];
    float acc = 0.f, dsum = 0.f;
    for (int eb = e0; eb < e1; eb += 8){
      int m = e1 - eb; if (m > 8) m = 8;
      int j[8];
      #pragma unroll
      for (int u=0;u<8;u++) j[u] = p.csrd[(u<m) ? eb+u : eb];
      uint2 hv[8]; float gv[8];
      #pragma unroll
      for (int u=0;u<8;u++){
        hv[u] = *(const uint2*)(p.h2h + (size_t)j[u]*256 + fo);
        gv[u] = __half2float(p.gh[(size_t)j[u]*64 + lane]);
      }
      float d[8];
      #pragma unroll
      for (int u=0;u<8;u++)
        d[u] = __builtin_amdgcn_fdot2(q1, as_h2(hv[u].y),
                __builtin_amdgcn_fdot2(q0, as_h2(hv[u].x), 0.f, false), false);
      #pragma unroll
      for (int mm=32; mm; mm>>=1){
        #pragma unroll
        for (int u=0;u<8;u++) d[u] += __shfl_xor(d[u], mm, 64);
      }
      #pragma unroll
      for (int u=0;u<8;u++){
        if (u < m){
          float we = Ei * __expf(d[u]);
          dsum += we;
          acc = fmaf(we - 1.f, gv[u], acc);
        }
      }
    }
    float inv = 1.0f / ((float)(p.n - (e1 - e0)) + dsum);
    p.hw3h[(size_t)i*64 + lane] = __float2half((p.sw3[lane] + acc) * inv);
  }
  grid.sync();

  // ---- P8: conv3 agg + bias + leaky + residual + LN + pool atomicMax ----
  for (int g4 = b; g4 < 2048; g4 += G){
    int c = g4*4 + w;
    float dc = p.dinv[c];
    float acc = 0.f;
    int e0 = p.ptrc[c], e1 = p.ptrc[c+1];
    for (int eb = e0; eb < e1; eb += 4){
      int m = e1 - eb; if (m > 4) m = 4;
      int r[4];
      #pragma unroll
      for (int u=0;u<4;u++) r[u] = p.csrc[(u<m) ? eb+u : eb];
      float sc[4]; __half hval[4];
      #pragma unroll
      for (int u=0;u<4;u++){
        sc[u] = p.dinv[r[u]];
        hval[u] = p.hw3h[(size_t)r[u]*64 + lane];
      }
      #pragma unroll
      for (int u=0;u<4;u++)
        if (u < m) acc = fmaf(sc[u], __half2float(hval[u]), acc);
    }
    float self = __half2float(p.hw3h[(size_t)c*64 + lane]);
    float v = leaky(dc*(dc*self + acc) + p.b3[lane]) + p.resid[(size_t)c*64 + lane];
    float s = v;
    #pragma unroll
    for (int mm=32; mm; mm>>=1) s += __shfl_xor(s, mm, 64);
    float mu = s * (1.0f/64.0f);
    float d = v - mu;
    float s2 = d*d;
    #pragma unroll
    for (int mm=32; mm; mm>>=1) s2 += __shfl_xor(s2, mm, 64);
    float zv = d * rsqrtf(s2*(1.0f/64.0f) + 1e-5f) * p.lng[lane] + p.lnb[lane];
    atomicMax(&p.poolpart[(c & 63)*64 + lane], fmap(zv));
  }
  grid.sync();

  // ---- P9: bucket reduce + 64x16 matvec (block 0) ----
  if (b == 0){
    int f = t & 63, g = t >> 6;
    unsigned mu = 0u;
    for (int bb = g; bb < 64; bb += 4) mu = max(mu, p.poolpart[bb*64 + f]);
    __shared__ unsigned sm[4][64];
    __shared__ float pp[64];
    sm[g][f] = mu;
    __syncthreads();
    if (g == 0)
      pp[f] = funmap(max(max(sm[0][f],sm[1][f]), max(sm[2][f],sm[3][f])));
    __syncthreads();
    if (t < 16){
      float a = p.bfv[t];
      #pragma unroll
      for (int ff=0; ff<64; ++ff) a = fmaf(pp[ff], p.Wf[ff*16 + t], a);
      p.out[t] = a;
    }
  }
}

extern "C" void kernel_launch(void* const* d_in, const int* in_sizes, int n_in,
                              void* d_out, int out_size, void* d_ws, size_t ws_size,
                              hipStream_t stream){
  const float* x   = (const float*)d_in[0];
  const int*   ei  = (const int*)d_in[1];
  const float* W1  = (const float*)d_in[2];
  const float* b1  = (const float*)d_in[3];
  const float* W2  = (const float*)d_in[4];
  const float* b2  = (const float*)d_in[5];
  const float* W3  = (const float*)d_in[6];
  const float* b3  = (const float*)d_in[7];
  const float* Wk  = (const float*)d_in[8];
  const float* bk  = (const float*)d_in[9];
  const float* Wq  = (const float*)d_in[10];
  const float* bq  = (const float*)d_in[11];
  const float* Wr  = (const float*)d_in[12];
  const float* br  = (const float*)d_in[13];
  const float* lng = (const float*)d_in[14];
  const float* lnb = (const float*)d_in[15];
  const float* Wf  = (const float*)d_in[16];
  const float* bfv = (const float*)d_in[17];
  float* out = (float*)d_out;

  const int n = NNODES, E = NEDGES;
  char* ws = (char*)d_ws; size_t off = 0;
  auto alloc = [&](size_t bytes)->void*{
    void* p = ws + off; off += (bytes + 255) & ~(size_t)255; return p;
  };
  __half* xh   = (__half*)alloc((size_t)n*128*2);
  __half* xw1h = (__half*)alloc((size_t)n*128*2);
  __half* h1h  = (__half*)alloc((size_t)n*128*2);
  __half* h1ah = (__half*)alloc((size_t)n*128*2);
  __half* h2h  = (__half*)alloc((size_t)n*256*2);
  __half* qth  = (__half*)alloc((size_t)n*256*2);
  __half* gh   = (__half*)alloc((size_t)n*64*2);
  __half* hw3h = (__half*)alloc((size_t)n*64*2);
  float*  resid= (float*)alloc((size_t)n*64*4);
  float*  dinv = (float*)alloc((size_t)n*4);
  __half* Wqh  = (__half*)alloc(256*256*2);
  __half* Wkh  = (__half*)alloc(256*256*2);
  __half* Wqkt = (__half*)alloc(256*256*2);
  __half* Wrt  = (__half*)alloc(128*64*2);
  __half* W1t  = (__half*)alloc(128*128*2);
  __half* W2t  = (__half*)alloc(128*256*2);
  __half* W3t  = (__half*)alloc(256*64*2);
  float*  bqk  = (float*)alloc(256*4);
  float*  wb   = (float*)alloc(256*4);
  float*  s0p  = (float*)alloc(4);
  int* ptrc = (int*)alloc((size_t)(n+1)*4);
  int* ptrr = (int*)alloc((size_t)(n+1)*4);
  int* curc = (int*)alloc((size_t)n*4);
  int* curr = (int*)alloc((size_t)n*4);
  int* csrc = (int*)alloc((size_t)E*4);
  int* csrd = (int*)alloc((size_t)E*4);
  // contiguous zero-init region: degc | degr | poolpart | sw3
  int* degc = (int*)alloc((size_t)n*4);
  int* degr = (int*)alloc((size_t)n*4);
  unsigned* poolpart = (unsigned*)alloc(64*64*4);
  float* sw3 = (float*)alloc(64*4);
  size_t zbytes = (size_t)n*4*2 + 64*64*4 + 256;

  // 0: zero degc/degr/poolpart/sw3
  hipMemsetAsync(degc, 0, zbytes, stream);
  // 1: conversions, transposes, degree atomics, small vectors
  k_pre<<<dim3(2720), 256, 0, stream>>>(x, Wq, Wk, Wr, W1, W2, W3, bq, bk, ei, E,
      xh, Wqh, Wkh, Wrt, W1t, W2t, W3t, bqk, wb, s0p, degc, degr);

  // 2: try the cooperative mega-kernel (512 blocks, 2/CU — comfortably co-resident)
  MegaP p;
  p.ei = ei; p.E = E; p.n = n;
  p.xh = xh; p.W1t = W1t; p.xw1h = xw1h;
  p.degc = degc; p.degr = degr;
  p.ptrc = ptrc; p.ptrr = ptrr; p.curc = curc; p.curr = curr; p.dinv = dinv;
  p.csrc = csrc; p.csrd = csrd;
  p.Wkh = Wkh; p.Wqh = Wqh; p.Wqkt = Wqkt;
  p.Wrt = Wrt; p.br = br; p.resid = resid;
  p.b1 = b1; p.h1h = h1h; p.h1ah = h1ah;
  p.W2t = W2t; p.b2 = b2; p.h2h = h2h;
  p.W3t = W3t; p.gh = gh; p.sw3 = sw3;
  p.bqk = bqk; p.qth = qth;
  p.wb = wb; p.s0p = s0p; p.hw3h = hw3h;
  p.b3 = b3; p.lng = lng; p.lnb = lnb;
  p.poolpart = poolpart;
  p.Wf = Wf; p.bfv = bfv; p.out = out;
  void* args[] = { &p };
  hipError_t err = hipLaunchCooperativeKernel((const void*)k_mega, dim3(512), dim3(256),
                                              args, 0, stream);
  if (err == hipSuccess) return;

  // Fallback: proven discrete pipeline (round-10). Deterministic per environment,
  // so every call does identical work.
  (void)hipGetLastError();   // clear sticky error from the failed launch attempt
  k_scan<<<dim3(2 + 256), 256, 0, stream>>>(degc, degr, ptrc, ptrr, curc, curr, dinv, n,
      xh, W1t, xw1h);
  k_mix1<<<dim3(E/256 + 16 + n/64), 256, 0, stream>>>(ei, curc, curr, csrc, csrd, E,
      Wkh, Wqh, Wqkt, xh, Wrt, br, resid);
  k_agg4<<<dim3(n/4), 256, 0, stream>>>(xw1h, ptrc, csrc, dinv, h1h, b1, 1);
  k_agg4<<<dim3(n/4), 256, 0, stream>>>(h1h, ptrc, csrc, dinv, h1ah, nullptr, 0);
  k_gemm<<<dim3(n/64, 4), 256, 0, stream>>>(h1ah, W2t, b2, nullptr, h2h, nullptr, 128, 256, 1);
  k_mix2<<<dim3(128 + 512), 256, 0, stream>>>(h2h, W3t, gh, sw3, Wqkt, bqk, qth);
  k_attn6<<<dim3(n/4), 256, 0, stream>>>(h2h, qth, gh, sw3, wb, s0p, ptrr, csrd, hw3h, n);
  k_zp4<<<dim3(n/4), 256, 0, stream>>>(hw3h, b3, ptrc, csrc, dinv, resid, lng, lnb, poolpart);
  k_final<<<1, 256, 0, stream>>>(poolpart, Wf, bfv, out);
}

// Round 13
// 251.372 us; speedup vs baseline: 3.3034x; 3.3034x over previous
//
#include <hip/hip_runtime.h>
#include <hip/hip_fp16.h>
#include <cstdint>
#include <cstddef>

#define NNODES 8192
#define NEDGES 262144

typedef _Float16 f16x8 __attribute__((ext_vector_type(8)));
typedef _Float16 h2v   __attribute__((ext_vector_type(2)));
typedef float    f32x4 __attribute__((ext_vector_type(4)));

__device__ __forceinline__ float leaky(float v){ return v > 0.f ? v : 0.01f*v; }

__device__ __forceinline__ unsigned fmap(float f){
  unsigned u = __float_as_uint(f);
  return (u & 0x80000000u) ? ~u : (u | 0x80000000u);
}
__device__ __forceinline__ float funmap(unsigned u){
  return (u & 0x80000000u) ? __uint_as_float(u & 0x7FFFFFFFu) : __uint_as_float(~u);
}
__device__ __forceinline__ h2v as_h2(unsigned u){
  union{ unsigned x; h2v h; } c; c.x = u; return c.h;
}

// ================= k_pre: conversions / transposes / zeroing / small vectors =======
// [0,1024): x->xh vec4 | [1024,1088): Wq | [1088,1152): Wk | [1152,1184): Wrt
// [1184,1248): W1t | [1248,1376): W2t | [1376,1440): W3t
// [1440,1504): zero degc/degr | [1504,1520): zero poolpart | 1520: zero sw3
// [1521,1777): smallvec (coalesced): bqk[c]=Wk_row_c.bq, wb[c]=Wq_row_c.bk; c0 adds s0
__global__ __launch_bounds__(256) void k_pre(
    const float* __restrict__ x, const float* __restrict__ Wq, const float* __restrict__ Wk,
    const float* __restrict__ Wr, const float* __restrict__ W1, const float* __restrict__ W2,
    const float* __restrict__ W3, const float* __restrict__ bq, const float* __restrict__ bk,
    __half* xh, __half* Wqh, __half* Wkh, __half* Wrt, __half* W1t, __half* W2t, __half* W3t,
    float* bqk, float* wb, float* s0p,
    int* degc, int* degr, float* sw3, unsigned* poolpart){
  int b = blockIdx.x, t = threadIdx.x;
  if (b < 1024){
    int base = (b*256 + t)*4;
    float4 xv = *(const float4*)(x + base);
    uint2 o;
    *(__half2*)&o.x = __floats2half2_rn(xv.x, xv.y);
    *(__half2*)&o.y = __floats2half2_rn(xv.z, xv.w);
    *(uint2*)(xh + base) = o;
  } else if (b < 1088){
    int base = ((b-1024)*256 + t)*4;
    float4 v = *(const float4*)(Wq + base);
    uint2 o;
    *(__half2*)&o.x = __floats2half2_rn(v.x, v.y);
    *(__half2*)&o.y = __floats2half2_rn(v.z, v.w);
    *(uint2*)(Wqh + base) = o;
  } else if (b < 1152){
    int base = ((b-1088)*256 + t)*4;
    float4 v = *(const float4*)(Wk + base);
    uint2 o;
    *(__half2*)&o.x = __floats2half2_rn(v.x, v.y);
    *(__half2*)&o.y = __floats2half2_rn(v.z, v.w);
    *(uint2*)(Wkh + base) = o;
  } else if (b < 1184){         // Wr[128][64] -> Wrt[64][128]
    int idx = (b-1152)*256 + t;
    int nn = idx >> 7, k = idx & 127;
    Wrt[idx] = __float2half(Wr[k*64 + nn]);
  } else if (b < 1248){         // W1[128][128] -> W1t[128][128]
    int idx = (b-1184)*256 + t;
    int nn = idx >> 7, k = idx & 127;
    W1t[idx] = __float2half(W1[k*128 + nn]);
  } else if (b < 1376){         // W2[128][256] -> W2t[256][128]
    int idx = (b-1248)*256 + t;
    int nn = idx >> 7, k = idx & 127;
    W2t[idx] = __float2half(W2[k*256 + nn]);
  } else if (b < 1440){         // W3[256][64] -> W3t[64][256]
    int idx = (b-1376)*256 + t;
    int nn = idx >> 8, k = idx & 255;
    W3t[idx] = __float2half(W3[k*64 + nn]);
  } else if (b < 1504){
    int idx = (b-1440)*256 + t;
    if (idx < 8192) degc[idx]=0; else degr[idx-8192]=0;
  } else if (b < 1520){
    poolpart[(b-1504)*256 + t] = 0u;
  } else if (b == 1520){
    if (t < 64) sw3[t]=0.f;
  } else {                      // smallvec: coalesced row read + block reduce
    int c = b - 1521;
    __shared__ float ra[256], rb[256], rc[256];
    ra[t] = Wk[c*256 + t] * bq[t];
    rb[t] = Wq[c*256 + t] * bk[t];
    if (c == 0) rc[t] = bq[t]*bk[t];
    __syncthreads();
    for (int off=128; off; off>>=1){
      if (t < off){
        ra[t] += ra[t+off];
        rb[t] += rb[t+off];
        if (c == 0) rc[t] += rc[t+off];
      }
      __syncthreads();
    }
    if (t == 0){
      bqk[c] = ra[0];
      wb[c]  = rb[0];
      if (c == 0) s0p[0] = rc[0];
    }
  }
}

// ---------------- MFMA GEMM tile (device): C64x64 = A[.,K] @ Bt[.,K]^T ----------------
__device__ __forceinline__ void gemm_tile(const __half* __restrict__ A,
    const __half* __restrict__ Bt, const float* __restrict__ bias,
    float* __restrict__ Cf, __half* __restrict__ Ch, float* __restrict__ csum,
    int K, int N, int act, int bx, int by,
    _Float16 (*As)[40], _Float16 (*Bs)[40], float* cs){
  int t = threadIdx.x, w = t>>6, lane = t&63;
  int m0 = bx*64, n0 = by*64;
  int quad = lane>>4, l15 = lane&15;
  int srow = t>>2, soff = (t&3)*8;
  f32x4 acc0 = {0.f,0.f,0.f,0.f}, acc1 = acc0, acc2 = acc0, acc3 = acc0;
  for (int k0 = 0; k0 < K; k0 += 32){
    *(uint4*)&As[srow][soff] = *(const uint4*)(A  + (size_t)(m0+srow)*K + k0 + soff);
    *(uint4*)&Bs[srow][soff] = *(const uint4*)(Bt + (size_t)(n0+srow)*K + k0 + soff);
    __syncthreads();
    f16x8 af = *(const f16x8*)&As[w*16 + l15][quad*8];
    f16x8 b0 = *(const f16x8*)&Bs[ 0 + l15][quad*8];
    f16x8 b1 = *(const f16x8*)&Bs[16 + l15][quad*8];
    f16x8 b2 = *(const f16x8*)&Bs[32 + l15][quad*8];
    f16x8 b3 = *(const f16x8*)&Bs[48 + l15][quad*8];
    acc0 = __builtin_amdgcn_mfma_f32_16x16x32_f16(af, b0, acc0, 0,0,0);
    acc1 = __builtin_amdgcn_mfma_f32_16x16x32_f16(af, b1, acc1, 0,0,0);
    acc2 = __builtin_amdgcn_mfma_f32_16x16x32_f16(af, b2, acc2, 0,0,0);
    acc3 = __builtin_amdgcn_mfma_f32_16x16x32_f16(af, b3, acc3, 0,0,0);
    __syncthreads();
  }
  f32x4 accs[4] = {acc0, acc1, acc2, acc3};
  if (csum){
    if (t < 64) cs[t] = 0.f;
    __syncthreads();
    #pragma unroll
    for (int nt=0; nt<4; ++nt){
      float p = accs[nt][0]+accs[nt][1]+accs[nt][2]+accs[nt][3];
      atomicAdd(&cs[nt*16 + l15], p);
    }
    __syncthreads();
    if (t < 64) atomicAdd(&csum[n0 + t], cs[t]);
  }
  #pragma unroll
  for (int nt=0; nt<4; ++nt){
    int col = n0 + nt*16 + l15;
    float bv = bias ? bias[col] : 0.f;
    #pragma unroll
    for (int r=0;r<4;r++){
      int row = m0 + w*16 + quad*4 + r;
      float v = accs[nt][r] + bv;
      if (act) v = leaky(v);
      if (Cf) Cf[(size_t)row*N + col] = v;
      if (Ch) Ch[(size_t)row*N + col] = __float2half(v);
    }
  }
}

// ---------------- degrees + xw1 = x@W1 gemm (transform-first conv1) ----------------
__global__ __launch_bounds__(256) void k_dg(const int* __restrict__ ei,
    int* degc, int* degr, int E,
    const __half* __restrict__ xh, const __half* __restrict__ W1t, __half* xw1h){
  __shared__ _Float16 As[64][40];
  __shared__ _Float16 Bs[64][40];
  int b = blockIdx.x;
  int DB = E/256;                       // 1024 degree blocks
  if (b < DB){
    int e = b*256 + threadIdx.x;
    atomicAdd(&degc[ei[E+e]], 1);
    atomicAdd(&degr[ei[e]],   1);
  } else {
    int bb = b - DB;                    // 256 tiles: M=8192(128), N=128(2)
    gemm_tile(xh, W1t, nullptr, nullptr, xw1h, nullptr, 128, 128, 0, bb>>1, bb&1, As, Bs, nullptr);
  }
}

// -------- shuffle-based exclusive scan + prep (block 0: col side w/ dinv; block 1: row side)
__global__ __launch_bounds__(1024) void k_scan(const int* __restrict__ degc,
    const int* __restrict__ degr, int* __restrict__ ptrc, int* __restrict__ ptrr,
    int* __restrict__ curc, int* __restrict__ curr, float* __restrict__ dinv, int n){
  const int* deg = blockIdx.x ? degr : degc;
  int* ptr = blockIdx.x ? ptrr : ptrc;
  int* cur = blockIdx.x ? curr : curc;
  int t = threadIdx.x, lane = t & 63, wid = t >> 6;   // 16 waves
  int base = t*8;
  int dv[8], loc[8]; int s = 0;
  #pragma unroll
  for (int q=0;q<8;q++){ dv[q]=deg[base+q]; loc[q]=s; s += dv[q]; }
  int sc = s;
  #pragma unroll
  for (int o=1;o<64;o<<=1){ int v = __shfl_up(sc, o, 64); if (lane >= o) sc += v; }
  __shared__ int wsum[16];
  if (lane==63) wsum[wid] = sc;
  __syncthreads();
  if (wid==0){
    int v = (lane<16) ? wsum[lane] : 0;
    #pragma unroll
    for (int o=1;o<16;o<<=1){ int u = __shfl_up(v, o, 64); if (lane >= o) v += u; }
    if (lane<16) wsum[lane] = v;
  }
  __syncthreads();
  int prev = sc - s + (wid ? wsum[wid-1] : 0);
  #pragma unroll
  for (int q=0;q<8;q++){
    int p = prev + loc[q];
    ptr[base+q] = p;
    cur[base+q] = p;
    if (!blockIdx.x) dinv[base+q] = rsqrtf((float)(dv[q]+1));
  }
  if (t==1023) ptr[n] = prev + s;
}

// ---------------- standalone GEMM wrapper ----------------
__global__ __launch_bounds__(256) void k_gemm(const __half* __restrict__ A,
    const __half* __restrict__ Bt, const float* __restrict__ bias,
    float* __restrict__ Cf, __half* __restrict__ Ch, float* __restrict__ csum,
    int K, int N, int act){
  __shared__ _Float16 As[64][40];
  __shared__ _Float16 Bs[64][40];
  __shared__ float cs[64];
  gemm_tile(A, Bt, bias, Cf, Ch, csum, K, N, act, blockIdx.x, blockIdx.y, As, Bs, cs);
}

// ---------------- mix1: CSR scatter + Wqkt gemm + resid gemm ----------------
__global__ __launch_bounds__(256) void k_mix1(const int* __restrict__ ei,
    int* curc, int* curr, int* csrc, int* csrd, int E,
    const __half* Wkh, const __half* Wqh, __half* Wqkt,
    const __half* xh, const __half* Wrt, const float* br, float* resid){
  __shared__ _Float16 As[64][40];
  __shared__ _Float16 Bs[64][40];
  int b = blockIdx.x;
  int SB = E/256;
  if (b < SB){
    int e = b*256 + threadIdx.x;
    int r = ei[e], c = ei[E+e];
    int p1 = atomicAdd(&curc[c],1); csrc[p1] = r;
    int p2 = atomicAdd(&curr[r],1); csrd[p2] = c;
  } else if (b < SB+16){
    int bb = b - SB;                    // Wqkt = (Wq@Wk^T)^T = Wk@Wq^T
    gemm_tile(Wkh, Wqh, nullptr, nullptr, Wqkt, nullptr, 256, 256, 0, bb&3, bb>>2, As, Bs, nullptr);
  } else {
    gemm_tile(xh, Wrt, br, resid, nullptr, nullptr, 128, 64, 0, b-(SB+16), 0, As, Bs, nullptr);
  }
}

// ---------------- mix2: G = h2@W3 (+colsum) and qt = h2@Wqk + bqk ----------------
__global__ __launch_bounds__(256) void k_mix2(const __half* h2h, const __half* W3t,
    __half* gh, float* sw3, const __half* Wqkt, const float* bqk, __half* qth){
  __shared__ _Float16 As[64][40];
  __shared__ _Float16 Bs[64][40];
  __shared__ float cs[64];
  int b = blockIdx.x;
  if (b < 128){
    gemm_tile(h2h, W3t, nullptr, nullptr, gh, sw3, 256, 64, 0, b, 0, As, Bs, cs);
  } else {
    int bb = b - 128;
    gemm_tile(h2h, Wqkt, bqk, nullptr, qth, nullptr, 256, 256, 0, bb>>2, bb&3, As, Bs, cs);
  }
}

// -------- GCN aggregation, F=128: 4 waves split edges, ILP-4, optional bias+leaky ------
__global__ __launch_bounds__(256) void k_agg128(const __half* __restrict__ in,
    const int* __restrict__ ptr, const int* __restrict__ src,
    const float* __restrict__ dinv, __half* __restrict__ outp,
    const float* __restrict__ bias, int act){
  int c = blockIdx.x, t = threadIdx.x, w = t>>6, lane = t&63;
  float dc = dinv[c];
  float2 acc = make_float2(0.f, 0.f);
  int e0 = ptr[c], e1 = ptr[c+1];
  for (int eb = e0 + w*4; eb < e1; eb += 16){
    int m = e1 - eb; if (m > 4) m = 4;
    int r[4];
    #pragma unroll
    for (int u=0;u<4;u++) r[u] = src[(u<m) ? eb+u : eb];
    float sc[4]; __half2 hv[4];
    #pragma unroll
    for (int u=0;u<4;u++){
      sc[u] = dinv[r[u]];
      hv[u] = *(const __half2*)(in + (size_t)r[u]*128 + lane*2);
    }
    #pragma unroll
    for (int u=0;u<4;u++){
      if (u < m){
        float2 h = __half22float2(hv[u]);
        acc.x = fmaf(sc[u], h.x, acc.x);
        acc.y = fmaf(sc[u], h.y, acc.y);
      }
    }
  }
  __shared__ float2 red[4][64];
  red[w][lane] = acc;
  __syncthreads();
  if (w == 0){
    float2 s = red[0][lane];
    float2 b1 = red[1][lane], b2 = red[2][lane], b3 = red[3][lane];
    s.x += b1.x + b2.x + b3.x;
    s.y += b1.y + b2.y + b3.y;
    float2 self = __half22float2(*(const __half2*)(in + (size_t)c*128 + lane*2));
    float ox = dc*(dc*self.x + s.x);
    float oy = dc*(dc*self.y + s.y);
    if (act){
      ox = leaky(ox + bias[lane*2]);
      oy = leaky(oy + bias[lane*2+1]);
    }
    *(__half2*)(outp + (size_t)c*128 + lane*2) = __floats2half2_rn(ox, oy);
  }
}

// ---------------- fused attention (projected 64-dim), wave-per-node, 8-edge ILP, fdot2 --
__global__ __launch_bounds__(256) void k_attn6(const __half* __restrict__ h2h,
    const __half* __restrict__ qth, const __half* __restrict__ gh,
    const float* __restrict__ sw3, const float* __restrict__ wb,
    const float* __restrict__ s0p, const int* __restrict__ ptrr,
    const int* __restrict__ csrd, __half* __restrict__ hw3h, int n){
  int w = threadIdx.x>>6, lane = threadIdx.x&63;
  int i = blockIdx.x*4 + w;
  int fo = lane*4;
  uint2 qtu = *(const uint2*)(qth + (size_t)i*256 + fo);
  h2v q0 = as_h2(qtu.x), q1 = as_h2(qtu.y);
  float4 wbv = *(const float4*)(wb + fo);
  uint2 hiu  = *(const uint2*)(h2h + (size_t)i*256 + fo);
  float2 hia = __half22float2(*(__half2*)&hiu.x);
  float2 hib = __half22float2(*(__half2*)&hiu.y);
  float pv = hia.x*wbv.x + hia.y*wbv.y + hib.x*wbv.z + hib.y*wbv.w;
  #pragma unroll
  for (int mm=32; mm; mm>>=1) pv += __shfl_xor(pv, mm, 64);
  float Ei = __expf(pv + s0p[0]);
  int e0 = ptrr[i], e1 = ptrr[i+1];
  float acc = 0.f, dsum = 0.f;
  for (int eb = e0; eb < e1; eb += 8){
    int m = e1 - eb; if (m > 8) m = 8;
    int j[8];
    #pragma unroll
    for (int u=0;u<8;u++) j[u] = csrd[(u<m) ? eb+u : eb];
    uint2 hv[8]; float gv[8];
    #pragma unroll
    for (int u=0;u<8;u++){
      hv[u] = *(const uint2*)(h2h + (size_t)j[u]*256 + fo);
      gv[u] = __half2float(gh[(size_t)j[u]*64 + lane]);
    }
    float d[8];
    #pragma unroll
    for (int u=0;u<8;u++)
      d[u] = __builtin_amdgcn_fdot2(q1, as_h2(hv[u].y),
              __builtin_amdgcn_fdot2(q0, as_h2(hv[u].x), 0.f, false), false);
    #pragma unroll
    for (int mm=32; mm; mm>>=1){
      #pragma unroll
      for (int u=0;u<8;u++) d[u] += __shfl_xor(d[u], mm, 64);
    }
    #pragma unroll
    for (int u=0;u<8;u++){
      if (u < m){
        float we = Ei * __expf(d[u]);
        dsum += we;
        acc = fmaf(we - 1.f, gv[u], acc);
      }
    }
  }
  float inv = 1.0f / ((float)(n - (e1 - e0)) + dsum);
  hw3h[(size_t)i*64 + lane] = __float2half((sw3[lane] + acc) * inv);
}

// ------- fused conv3 agg + bias + leaky + residual + LayerNorm + pool atomicMax -------
__global__ __launch_bounds__(256) void k_zp(const __half* __restrict__ hw3h,
    const float* __restrict__ b3, const int* __restrict__ ptrc,
    const int* __restrict__ csrc, const float* __restrict__ dinv,
    const float* __restrict__ resid, const float* __restrict__ lng,
    const float* __restrict__ lnb, unsigned* __restrict__ poolpart){
  int c = blockIdx.x, t = threadIdx.x, w = t>>6, lane = t&63;
  float dc = dinv[c];
  float acc = 0.f;
  int e0 = ptrc[c], e1 = ptrc[c+1];
  for (int eb = e0 + w*4; eb < e1; eb += 16){
    int m = e1 - eb; if (m > 4) m = 4;
    int r[4];
    #pragma unroll
    for (int u=0;u<4;u++) r[u] = csrc[(u<m) ? eb+u : eb];
    float sc[4]; __half hval[4];
    #pragma unroll
    for (int u=0;u<4;u++){
      sc[u] = dinv[r[u]];
      hval[u] = hw3h[(size_t)r[u]*64 + lane];
    }
    #pragma unroll
    for (int u=0;u<4;u++)
      if (u < m) acc = fmaf(sc[u], __half2float(hval[u]), acc);
  }
  __shared__ float red[4][64];
  red[w][lane] = acc;
  __syncthreads();
  if (w == 0){
    acc = red[0][lane]+red[1][lane]+red[2][lane]+red[3][lane];
    float self = __half2float(hw3h[(size_t)c*64 + lane]);
    float v = leaky(dc*(dc*self + acc) + b3[lane]) + resid[(size_t)c*64 + lane];
    float s = v;
    #pragma unroll
    for (int mm=32; mm; mm>>=1) s += __shfl_xor(s, mm, 64);
    float mu = s * (1.0f/64.0f);
    float d = v - mu;
    float s2 = d*d;
    #pragma unroll
    for (int mm=32; mm; mm>>=1) s2 += __shfl_xor(s2, mm, 64);
    float zv = d * rsqrtf(s2*(1.0f/64.0f) + 1e-5f) * lng[lane] + lnb[lane];
    atomicMax(&poolpart[(c & 63)*64 + lane], fmap(zv));
  }
}

// ---------------- final: reduce poolpart buckets + 64x16 matvec ----------------
__global__ __launch_bounds__(256) void k_final(const unsigned* __restrict__ poolpart,
    const float* __restrict__ Wf, const float* __restrict__ bfv, float* __restrict__ out){
  int t = threadIdx.x, f = t & 63, g = t >> 6;
  unsigned mu = 0u;
  for (int b = g; b < 64; b += 4) mu = max(mu, poolpart[b*64 + f]);
  __shared__ unsigned sm[4][64];
  __shared__ float p[64];
  sm[g][f] = mu;
  __syncthreads();
  if (g == 0)
    p[f] = funmap(max(max(sm[0][f],sm[1][f]), max(sm[2][f],sm[3][f])));
  __syncthreads();
  if (t < 16){
    float a = bfv[t];
    #pragma unroll
    for (int ff=0; ff<64; ++ff) a = fmaf(p[ff], Wf[ff*16 + t], a);
    out[t] = a;
  }
}

extern "C" void kernel_launch(void* const* d_in, const int* in_sizes, int n_in,
                              void* d_out, int out_size, void* d_ws, size_t ws_size,
                              hipStream_t stream){
  const float* x   = (const float*)d_in[0];
  const int*   ei  = (const int*)d_in[1];
  const float* W1  = (const float*)d_in[2];
  const float* b1  = (const float*)d_in[3];
  const float* W2  = (const float*)d_in[4];
  const float* b2  = (const float*)d_in[5];
  const float* W3  = (const float*)d_in[6];
  const float* b3  = (const float*)d_in[7];
  const float* Wk  = (const float*)d_in[8];
  const float* bk  = (const float*)d_in[9];
  const float* Wq  = (const float*)d_in[10];
  const float* bq  = (const float*)d_in[11];
  const float* Wr  = (const float*)d_in[12];
  const float* br  = (const float*)d_in[13];
  const float* lng = (const float*)d_in[14];
  const float* lnb = (const float*)d_in[15];
  const float* Wf  = (const float*)d_in[16];
  const float* bfv = (const float*)d_in[17];
  float* out = (float*)d_out;

  const int n = NNODES, E = NEDGES;
  char* ws = (char*)d_ws; size_t off = 0;
  auto alloc = [&](size_t bytes)->void*{
    void* p = ws + off; off += (bytes + 255) & ~(size_t)255; return p;
  };
  __half* xh   = (__half*)alloc((size_t)n*128*2);
  __half* xw1h = (__half*)alloc((size_t)n*128*2);
  __half* h1h  = (__half*)alloc((size_t)n*128*2);
  __half* h1ah = (__half*)alloc((size_t)n*128*2);
  __half* h2h  = (__half*)alloc((size_t)n*256*2);
  __half* qth  = (__half*)alloc((size_t)n*256*2);
  __half* gh   = (__half*)alloc((size_t)n*64*2);
  __half* hw3h = (__half*)alloc((size_t)n*64*2);
  float*  resid= (float*)alloc((size_t)n*64*4);
  float*  dinv = (float*)alloc((size_t)n*4);
  float*  sw3  = (float*)alloc(64*4);
  __half* Wqh  = (__half*)alloc(256*256*2);
  __half* Wkh  = (__half*)alloc(256*256*2);
  __half* Wqkt = (__half*)alloc(256*256*2);
  __half* Wrt  = (__half*)alloc(128*64*2);
  __half* W1t  = (__half*)alloc(128*128*2);
  __half* W2t  = (__half*)alloc(128*256*2);
  __half* W3t  = (__half*)alloc(256*64*2);
  float*  bqk  = (float*)alloc(256*4);
  float*  wb   = (float*)alloc(256*4);
  float*  s0p  = (float*)alloc(4);
  int* degc = (int*)alloc((size_t)n*4);
  int* degr = (int*)alloc((size_t)n*4);
  int* ptrc = (int*)alloc((size_t)(n+1)*4);
  int* ptrr = (int*)alloc((size_t)(n+1)*4);
  int* curc = (int*)alloc((size_t)n*4);
  int* curr = (int*)alloc((size_t)n*4);
  int* csrc = (int*)alloc((size_t)E*4);
  int* csrd = (int*)alloc((size_t)E*4);
  unsigned* poolpart = (unsigned*)alloc(64*64*4);

  // 1: conversions, transposes, zeroing, small vectors
  k_pre<<<dim3(1777), 256, 0, stream>>>(x, Wq, Wk, Wr, W1, W2, W3, bq, bk,
      xh, Wqh, Wkh, Wrt, W1t, W2t, W3t, bqk, wb, s0p, degc, degr, sw3, poolpart);
  // 2: degrees + xw1 = x@W1 (transform-first conv1, overlapped)
  k_dg <<<dim3(E/256 + 256), 256, 0, stream>>>(ei, degc, degr, E, xh, W1t, xw1h);
  // 3: scans (+dinv, cursors)
  k_scan<<<2, 1024, 0, stream>>>(degc, degr, ptrc, ptrr, curc, curr, dinv, n);
  // 4: CSR scatter + Wqkt gemm + resid gemm
  k_mix1<<<dim3(E/256 + 16 + n/64), 256, 0, stream>>>(ei, curc, curr, csrc, csrd, E,
      Wkh, Wqh, Wqkt, xh, Wrt, br, resid);
  // 5: conv1 aggregate + bias + leaky -> h1
  k_agg128<<<n, 256, 0, stream>>>(xw1h, ptrc, csrc, dinv, h1h, b1, 1);
  // 6: conv2 aggregate (128-wide, pre-transform)
  k_agg128<<<n, 256, 0, stream>>>(h1h, ptrc, csrc, dinv, h1ah, nullptr, 0);
  // 7: conv2 transform: h2 = leaky(h1a@W2 + b2)
  k_gemm<<<dim3(n/64, 4), 256, 0, stream>>>(h1ah, W2t, b2, nullptr, h2h, nullptr, 128, 256, 1);
  // 8: G = h2@W3 (+colsum) and qt = h2@Wqk + bqk
  k_mix2<<<dim3(128 + 512), 256, 0, stream>>>(h2h, W3t, gh, sw3, Wqkt, bqk, qth);
  // 9: fused attention -> hw3h (projected 64-dim)
  k_attn6<<<dim3(n/4), 256, 0, stream>>>(h2h, qth, gh, sw3, wb, s0p, ptrr, csrd, hw3h, n);
  // 10: conv3 agg + residual + LN + pool atomicMax
  k_zp<<<n, 256, 0, stream>>>(hw3h, b3, ptrc, csrc, dinv, resid, lng, lnb, poolpart);
  // 11: bucket reduce + matvec
  k_final<<<1, 256, 0, stream>>>(poolpart, Wf, bfv, out);
}